// Round 4
// baseline (21760.165 us; speedup 1.0000x reference)
//
#include <hip/hip_runtime.h>
#include <math.h>

#define VOCN 32000
#define HN 512
#define TN 256
#define BN 64
#define MAXLENN 32
#define SOSW 1

// ---------------- workspace layout (float/int32 units) ----------------
#define WS_FLAG     0                       // 256 blocks * 32 ints (128B line each)
#define WS_REL      8192                    // 8 release lines * 16 ints (+pad to 256)
#define WS_H        8448                    // h buffers [2 parity][2 layer][64][512]
#define WS_CELLS    (WS_H + 131072)         // 32 steps * 64 u64 argmax cells (zeroed)
#define WS_AVG      (WS_CELLS + 4096)       // 64 floats: avg_W . top (per step)
#define WS_A        (WS_AVG + 64)           // a[64][256]  (b-major)
#define WS_APPLIED  (WS_A + 16384)          // [64][512]
#define WS_COMB     (WS_APPLIED + 32768)    // [64][512]
#define WS_GRUOUT   (WS_COMB + 32768)       // [256][64][512]
#define WS_ZERO_BYTES ((WS_CELLS + 4096) * 4) // zero flags + rel + h + cells

typedef float f4 __attribute__((ext_vector_type(4)));

__device__ __forceinline__ f4 ld4(const float* p) { return *(const f4*)p; }
__device__ __forceinline__ float dot4(f4 a, f4 b, float acc) {
  acc = fmaf(a.x, b.x, acc); acc = fmaf(a.y, b.y, acc);
  acc = fmaf(a.z, b.z, acc); acc = fmaf(a.w, b.w, acc); return acc;
}
__device__ __forceinline__ f4 relu4(f4 v) {
  v.x = fmaxf(v.x, 0.f); v.y = fmaxf(v.y, 0.f);
  v.z = fmaxf(v.z, 0.f); v.w = fmaxf(v.w, 0.f); return v;
}
__device__ __forceinline__ float sigmoidf_(float x) { return 1.f / (1.f + expf(-x)); }

// ---- agent-coherent (L1+L2-bypassing, sc0 sc1) loads/stores, all BLOCKING
// (waitcnt inside the asm) — the proven-safe form. They hit the coherence
// point (L3) directly; no cache-flush fences needed for cross-XCD visibility.
__device__ __forceinline__ float ldcg(const float* p) {
  float v;
  asm volatile("global_load_dword %0, %1, off sc0 sc1\n\ts_waitcnt vmcnt(0)"
               : "=&v"(v) : "v"(p) : "memory");
  return v;
}
__device__ __forceinline__ void stcg(float* p, float v) {
  asm volatile("global_store_dword %0, %1, off sc0 sc1" :: "v"(p), "v"(v) : "memory");
}
__device__ __forceinline__ void ldcg_b4(const float* p0, const float* p1,
                                        const float* p2, const float* p3,
                                        f4& v0, f4& v1, f4& v2, f4& v3) {
  asm volatile(
      "global_load_dwordx4 %0, %4, off sc0 sc1\n\t"
      "global_load_dwordx4 %1, %5, off sc0 sc1\n\t"
      "global_load_dwordx4 %2, %6, off sc0 sc1\n\t"
      "global_load_dwordx4 %3, %7, off sc0 sc1\n\t"
      "s_waitcnt vmcnt(0)"
      : "=&v"(v0), "=&v"(v1), "=&v"(v2), "=&v"(v3)
      : "v"(p0), "v"(p1), "v"(p2), "v"(p3)
      : "memory");
}
__device__ __forceinline__ void ldcg_b8(const float* p0, const float* p1,
    const float* p2, const float* p3, const float* p4, const float* p5,
    const float* p6, const float* p7,
    f4& v0, f4& v1, f4& v2, f4& v3, f4& v4, f4& v5, f4& v6, f4& v7) {
  asm volatile(
      "global_load_dwordx4 %0, %8, off sc0 sc1\n\t"
      "global_load_dwordx4 %1, %9, off sc0 sc1\n\t"
      "global_load_dwordx4 %2, %10, off sc0 sc1\n\t"
      "global_load_dwordx4 %3, %11, off sc0 sc1\n\t"
      "global_load_dwordx4 %4, %12, off sc0 sc1\n\t"
      "global_load_dwordx4 %5, %13, off sc0 sc1\n\t"
      "global_load_dwordx4 %6, %14, off sc0 sc1\n\t"
      "global_load_dwordx4 %7, %15, off sc0 sc1\n\t"
      "s_waitcnt vmcnt(0)"
      : "=&v"(v0), "=&v"(v1), "=&v"(v2), "=&v"(v3),
        "=&v"(v4), "=&v"(v5), "=&v"(v6), "=&v"(v7)
      : "v"(p0), "v"(p1), "v"(p2), "v"(p3), "v"(p4), "v"(p5), "v"(p6), "v"(p7)
      : "memory");
}
// 8 contiguous quads (128B) from one base pointer
__device__ __forceinline__ void ldcg_row8(const float* p, f4 (&v)[8]) {
  asm volatile(
      "global_load_dwordx4 %0, %8, off sc0 sc1\n\t"
      "global_load_dwordx4 %1, %8, off offset:16 sc0 sc1\n\t"
      "global_load_dwordx4 %2, %8, off offset:32 sc0 sc1\n\t"
      "global_load_dwordx4 %3, %8, off offset:48 sc0 sc1\n\t"
      "global_load_dwordx4 %4, %8, off offset:64 sc0 sc1\n\t"
      "global_load_dwordx4 %5, %8, off offset:80 sc0 sc1\n\t"
      "global_load_dwordx4 %6, %8, off offset:96 sc0 sc1\n\t"
      "global_load_dwordx4 %7, %8, off offset:112 sc0 sc1\n\t"
      "s_waitcnt vmcnt(0)"
      : "=&v"(v[0]), "=&v"(v[1]), "=&v"(v[2]), "=&v"(v[3]),
        "=&v"(v[4]), "=&v"(v[5]), "=&v"(v[6]), "=&v"(v[7])
      : "v"(p)
      : "memory");
}

// Grid barrier (512-thread-safe: only tid<256 poll flag slots; flag region has
// 256 block slots). Entry drains vmcnt so all coherent stores/atomics retire.
__device__ __forceinline__ void grid_barrier(int* wsi, int gen) {
  asm volatile("s_waitcnt vmcnt(0) lgkmcnt(0)" ::: "memory");
  __syncthreads();
  const int bid = blockIdx.x;
  const int tid = threadIdx.x;
  if (bid == 0) {
    if (tid == 0)
      __hip_atomic_store(wsi + WS_FLAG, gen, __ATOMIC_RELAXED, __HIP_MEMORY_SCOPE_AGENT);
    int* fp = wsi + WS_FLAG + (tid & 255) * 32;
    for (;;) {
      int v = gen;
      if (tid < 256)
        v = __hip_atomic_load(fp, __ATOMIC_RELAXED, __HIP_MEMORY_SCOPE_AGENT);
      if (__syncthreads_and(v >= gen)) break;
      __builtin_amdgcn_s_sleep(2);
    }
    if (tid < 8)
      __hip_atomic_store(wsi + WS_REL + tid * 16, gen, __ATOMIC_RELAXED, __HIP_MEMORY_SCOPE_AGENT);
    __syncthreads();
  } else {
    if (tid == 0) {
      __hip_atomic_store(wsi + WS_FLAG + bid * 32, gen, __ATOMIC_RELAXED, __HIP_MEMORY_SCOPE_AGENT);
      int* rp = wsi + WS_REL + (bid & 7) * 16;
      while (__hip_atomic_load(rp, __ATOMIC_RELAXED, __HIP_MEMORY_SCOPE_AGENT) < gen)
        __builtin_amdgcn_s_sleep(2);
    }
    __syncthreads();
  }
}

// Packed-argmax key helpers: key = ord(val)<<32 | (0xFFFFFFFF - idx).
// ord() is a monotone bijection float->u32; max key == max val, ties -> min idx.
__device__ __forceinline__ unsigned ord_enc(float v) {
  unsigned u = __float_as_uint(v);
  return (u & 0x80000000u) ? ~u : (u | 0x80000000u);
}
__device__ __forceinline__ float ord_dec(unsigned k32) {
  unsigned u = (k32 & 0x80000000u) ? (k32 ^ 0x80000000u) : ~k32;
  return __uint_as_float(u);
}
__device__ __forceinline__ int decode_word(const unsigned long long* cell) {
  unsigned long long key = __hip_atomic_load(cell, __ATOMIC_RELAXED,
                                             __HIP_MEMORY_SCOPE_AGENT);
  int wb = (int)(0xFFFFFFFFu - (unsigned)(key & 0xFFFFFFFFull));
  return wb < 0 ? 0 : (wb > VOCN - 1 ? VOCN - 1 : wb);
}

// GRU layer phase — 512 threads/block, 64 blocks (jg = block id).
// Both batch halves packed in one block via bg = tid>>8, each with its own
// 32KB LDS half. Per-thread structure identical to the proven 256-thread form.
__device__ __forceinline__ void gru_phase(
    const float* __restrict__ x_base, const int* __restrict__ tok,
    const float* __restrict__ h_rows,
    const float* __restrict__ Wih, const float* __restrict__ Whh,
    const float* __restrict__ bih, const float* __restrict__ bhh,
    float* __restrict__ h_out, float* __restrict__ aux_out,
    int jg, float* lds)
{
  const int tid = threadIdx.x;
  const int tid2 = tid & 255;
  const int bg = tid >> 8;             // batch half
  f4* x4l = (f4*)lds + (bg << 11);     // 2048 quads per half (32KB)
  f4* h4l = x4l + 1024;

  const float* xp[4]; const float* hp[4]; int loff[4];
#pragma unroll
  for (int i = 0; i < 4; ++i) {
    int tau = tid2 + (i << 8);
    int b = tau >> 5;        // [0,32)
    int kq = tau & 31;
    int gb = bg * 32 + b;
    const float* xr = tok ? (x_base + (size_t)tok[gb] * HN) : (x_base + (size_t)gb * HN);
    xp[i] = xr + (kq << 2);
    hp[i] = h_rows + (size_t)gb * HN + (kq << 2);
    loff[i] = (b << 5) + (kq ^ (b & 7));
  }
  const bool cachedx = (tok != nullptr);  // x = embedding table -> cached; also relu flag
  f4 pxv[4], phv[4];
  if (cachedx) {
#pragma unroll
    for (int i = 0; i < 4; ++i) pxv[i] = ld4(xp[i]);
    ldcg_b4(hp[0], hp[1], hp[2], hp[3], phv[0], phv[1], phv[2], phv[3]);
  } else {
    ldcg_b8(xp[0], xp[1], xp[2], xp[3], hp[0], hp[1], hp[2], hp[3],
            pxv[0], pxv[1], pxv[2], pxv[3], phv[0], phv[1], phv[2], phv[3]);
  }

  const int bl = tid2 & 31;
  const int jl = tid2 >> 5;         // [0,8)
  const int j = (jg << 3) + jl;     // [0,512)
  const float* wi0 = Wih + (size_t)j * HN;
  const float* wi1 = Wih + (size_t)(512 + j) * HN;
  const float* wi2 = Wih + (size_t)(1024 + j) * HN;
  const float* wh0 = Whh + (size_t)j * HN;
  const float* wh1 = Whh + (size_t)(512 + j) * HN;
  const float* wh2 = Whh + (size_t)(1024 + j) * HN;
  float ax0 = 0.f, ax1 = 0.f, ax2 = 0.f, ah0 = 0.f, ah1 = 0.f, ah2 = 0.f;
  const int rdbase = bl << 5;
  const int rdx = bl & 7;

#pragma unroll 1
  for (int ch = 0; ch < 4; ++ch) {
    __syncthreads();
#pragma unroll
    for (int i = 0; i < 4; ++i) {
      x4l[loff[i]] = cachedx ? relu4(pxv[i]) : pxv[i];
      h4l[loff[i]] = phv[i];
    }
    __syncthreads();
    if (ch < 3) {
      const int off = (ch + 1) * 128;
      if (cachedx) {
#pragma unroll
        for (int i = 0; i < 4; ++i) pxv[i] = ld4(xp[i] + off);
        ldcg_b4(hp[0] + off, hp[1] + off, hp[2] + off, hp[3] + off,
                phv[0], phv[1], phv[2], phv[3]);
      } else {
        ldcg_b8(xp[0] + off, xp[1] + off, xp[2] + off, xp[3] + off,
                hp[0] + off, hp[1] + off, hp[2] + off, hp[3] + off,
                pxv[0], pxv[1], pxv[2], pxv[3], phv[0], phv[1], phv[2], phv[3]);
      }
    }
    const int k0 = ch << 7;
#pragma unroll 4
    for (int kq = 0; kq < 32; ++kq) {
      f4 xv = x4l[rdbase + (kq ^ rdx)];
      f4 hv = h4l[rdbase + (kq ^ rdx)];
      const int kk = k0 + (kq << 2);
      ax0 = dot4(xv, ld4(wi0 + kk), ax0);
      ah0 = dot4(hv, ld4(wh0 + kk), ah0);
      ax1 = dot4(xv, ld4(wi1 + kk), ax1);
      ah1 = dot4(hv, ld4(wh1 + kk), ah1);
      ax2 = dot4(xv, ld4(wi2 + kk), ax2);
      ah2 = dot4(hv, ld4(wh2 + kk), ah2);
    }
  }
  const int gb = bg * 32 + bl;
  const float hold = ldcg(h_rows + (size_t)gb * HN + j);
  const float r = sigmoidf_(ax0 + bih[j] + ah0 + bhh[j]);
  const float z = sigmoidf_(ax1 + bih[512 + j] + ah1 + bhh[512 + j]);
  const float n = tanhf(ax2 + bih[1024 + j] + r * (ah2 + bhh[1024 + j]));
  const float hv = (1.f - z) * n + z * hold;
  stcg(h_out + (size_t)gb * HN + j, hv);
  if (aux_out) stcg(aux_out + (size_t)gb * HN + j, hv);
}

// D1 (512 thr): a[b, tau=bid] = relu(cat(e, sv) @ attn_W[tau] + attn_b[tau]).
// 8 q-waves x 192-K ranges. Word decoded from the step-(s-1) atomic cells
// (once per b by tid<64, shared via LDS). Block 0 also finalizes step s-1's
// q output (global argmax is complete after the post-d6 barrier).
__device__ __forceinline__ void d1_attn(
    const float* __restrict__ emb_dec, const unsigned long long* __restrict__ cells,
    int s, const float* __restrict__ hflat, const float* __restrict__ attn_W,
    const float* __restrict__ attn_b, float* __restrict__ a_buf,
    const float* __restrict__ avg_buf, float* __restrict__ qs_base,
    int bid, float* lds)
{
  const int tid = threadIdx.x;
  const int b = tid & 63, q = tid >> 6;     // q in [0,8)
  int* wlds = (int*)(lds + 576);            // 64 decoded words
  if (s > 0 && tid < 64)
    wlds[tid] = decode_word(cells + (size_t)(s - 1) * 64 + tid);
  if (s > 0 && bid == 0 && tid < 64) {
    unsigned long long key = __hip_atomic_load(cells + (size_t)(s - 1) * 64 + tid,
                                               __ATOMIC_RELAXED, __HIP_MEMORY_SCOPE_AGENT);
    qs_base[(size_t)(s - 1) * BN + tid] = ord_dec((unsigned)(key >> 32)) + ldcg(avg_buf + tid);
  }
  __syncthreads();
  const int wb = (s == 0) ? SOSW : wlds[b];
  const float* er = emb_dec + (size_t)wb * HN;
  const float* hr = hflat + b * 1024;
  const float* wr = attn_W + (size_t)bid * 1536;
  float acc = 0.f;
  const int kbeg = q * 192, kend = kbeg + 192;
  int k = kbeg;
  const int kc = (kend < 512) ? kend : 512;
  for (; k < kc; k += 4)
    acc = dot4(relu4(ld4(er + k)), ld4(wr + k), acc);
  if (k < 512) k = 512;
  for (; k < kend; k += 32) {
    f4 hv[8]; ldcg_row8(hr + (k - 512), hv);
#pragma unroll
    for (int jq = 0; jq < 8; ++jq)
      acc = dot4(hv[jq], ld4(wr + k + (jq << 2)), acc);
  }
  __syncthreads();                          // wlds consumed; reuse lds for partials
  lds[(b << 3) + q] = acc;
  __syncthreads();
  if (tid < 64) {
    float v = 0.f;
#pragma unroll
    for (int i = 0; i < 8; ++i) v += lds[(tid << 3) + i];
    v += attn_b[bid];
    stcg(a_buf + tid * 256 + bid, fmaxf(v, 0.f));
  }
}

// D2 (512 thr): applied[b,h] = sum_t a[b,t]*gru_out[t,b,h]; 4 t-quarters.
__device__ __forceinline__ void d2_applied(const float* __restrict__ a_buf,
    const float* __restrict__ gru_out, float* __restrict__ applied, int bid, float* lds)
{
  const int tid = threadIdx.x;
  const int b = bid & 63, hc = bid >> 6;
  f4* al4 = (f4*)lds;          // 64 quads = a[b][0..256)
  float* al = lds;
  float* red = lds + 256;      // 512 partials
  if (tid < 64) {
    f4 av;
    const float* p = a_buf + b * 256 + (tid << 2);
    asm volatile("global_load_dwordx4 %0, %1, off sc0 sc1\n\ts_waitcnt vmcnt(0)"
                 : "=&v"(av) : "v"(p) : "memory");
    al4[tid] = av;
  }
  __syncthreads();
  const int hl = tid & 127, th = tid >> 7;  // th in [0,4)
  const int hh = (hc << 7) + hl;
  const float* gp = gru_out + (size_t)b * HN + hh;
  float acc = 0.f;
  const int t0 = th << 6;
#pragma unroll 4
  for (int t = t0; t < t0 + 64; ++t)
    acc = fmaf(al[t], gp[(size_t)t * (BN * HN)], acc);
  red[tid] = acc;
  __syncthreads();
  if (tid < 128)
    stcg(applied + (size_t)b * HN + (hc << 7) + tid,
         red[tid] + red[tid + 128] + red[tid + 256] + red[tid + 384]);
}

// D3 (512 thr): comb[b,col] for 2 cols/block; both columns share one input
// load; 8 q-waves x 128-K ranges.
__device__ __forceinline__ void d3_comb(const float* __restrict__ emb_dec,
    const unsigned long long* __restrict__ cells, int s,
    const float* __restrict__ applied, const float* __restrict__ comb_W,
    const float* __restrict__ comb_b, float* __restrict__ comb, int bid, float* lds)
{
  const int tid = threadIdx.x;
  const int b = tid & 63, q = tid >> 6;   // q in [0,8)
  int* wlds = (int*)(lds + 1088);         // 64 decoded words (past partial area)
  if (s > 0 && tid < 64)
    wlds[tid] = decode_word(cells + (size_t)(s - 1) * 64 + tid);
  __syncthreads();
  const int wb = (s == 0) ? SOSW : wlds[b];
  const float* er = emb_dec + (size_t)wb * HN;
  const float* apr = applied + (size_t)b * HN;
  const int col0 = bid << 1;
  const float* w0 = comb_W + (size_t)col0 * 1024;
  const float* w1 = w0 + 1024;
  float a0 = 0.f, a1 = 0.f;
  const int kb = q << 7;
  if (q < 4) {                            // emb region [0,512)
    for (int k = kb; k < kb + 128; k += 4) {
      f4 e = relu4(ld4(er + k));
      a0 = dot4(e, ld4(w0 + k), a0);
      a1 = dot4(e, ld4(w1 + k), a1);
    }
  } else {                                // applied region [512,1024): 4 rows
#pragma unroll 1
    for (int r = 0; r < 4; ++r) {
      f4 av[8]; ldcg_row8(apr + (kb - 512) + (r << 5), av);
#pragma unroll
      for (int jq = 0; jq < 8; ++jq) {
        a0 = dot4(av[jq], ld4(w0 + kb + (r << 5) + (jq << 2)), a0);
        a1 = dot4(av[jq], ld4(w1 + kb + (r << 5) + (jq << 2)), a1);
      }
    }
  }
  __syncthreads();                        // wlds consumed
  lds[(b << 3) + q] = a0;
  lds[512 + (b << 3) + q] = a1;
  __syncthreads();
  if (tid < 128) {
    const int cc = tid >> 6, b2 = tid & 63;
    const float* base = lds + cc * 512;
    float v = 0.f;
#pragma unroll
    for (int i = 0; i < 8; ++i) v += base[(b2 << 3) + i];
    v += comb_b[col0 + cc];
    stcg(comb + (size_t)b2 * HN + col0 + cc, fmaxf(v, 0.f));
  }
}

// D6 v4 (512 thr): per-block partial argmax over its 125 adv_W columns.
// Register blocking: thread (rp,co) owns rows {2rp,2rp+1} x cols {co*8..+8}
// -> each weight LDS read feeds 8 fmaf (vs 4 before), each top read 32.
// tl = top[64][32] (32KB, XOR-swizzled); wl = advW[128 cols][16 kq] (32KB,
// swizzled by (col>>3)&7 so the 16 per-wave col addresses spread 2/bank=free).
// Result goes straight to the packed-u64 atomicMax cell (d7 folded away);
// block 0 also accumulates avg_W . top from the staged tl.
__device__ __forceinline__ void d6_values(const float* __restrict__ top,
    const float* __restrict__ adv_W, const float* __restrict__ avg_W,
    unsigned long long* __restrict__ cellsS, float* __restrict__ avg_buf,
    int bid, float* lds)
{
  const int tid = threadIdx.x;
  const int c0 = bid * 125;
  f4* tl = (f4*)lds;            // 2048 quads (32KB)
  f4* wl = ((f4*)lds) + 2048;   // 2048 quads (32KB)

  const float* tp[4]; int loff[4];
#pragma unroll
  for (int i = 0; i < 4; ++i) {
    int tau = tid + (i << 9);                 // [0,2048)
    int b = tau >> 5, kq = tau & 31;
    tp[i] = top + b * HN + (kq << 2);
    loff[i] = (b << 5) + (kq ^ (b & 7));
  }
  f4 pv[4];
  ldcg_b4(tp[0], tp[1], tp[2], tp[3], pv[0], pv[1], pv[2], pv[3]);

  const int rp = tid >> 4;      // [0,32) row pair
  const int co = tid & 15;      // [0,16) col oct
  const int r0 = rp << 1;
  float acc0[8], acc1[8];
#pragma unroll
  for (int i = 0; i < 8; ++i) { acc0[i] = 0.f; acc1[i] = 0.f; }
  float avgacc = 0.f;

#pragma unroll 1
  for (int ch = 0; ch < 4; ++ch) {
    __syncthreads();
#pragma unroll
    for (int i = 0; i < 4; ++i) tl[loff[i]] = pv[i];
    __syncthreads();
    if (ch < 3) {
      const int off = (ch + 1) * 128;
      ldcg_b4(tp[0] + off, tp[1] + off, tp[2] + off, tp[3] + off,
              pv[0], pv[1], pv[2], pv[3]);
    }
    if (bid == 0 && tid < 64) {             // avg partial for row tid
#pragma unroll 4
      for (int kq = 0; kq < 32; ++kq)
        avgacc = dot4(tl[(tid << 5) + (kq ^ (tid & 7))],
                      ld4(avg_W + (ch << 7) + (kq << 2)), avgacc);
    }
#pragma unroll 1
    for (int w = 0; w < 2; ++w) {
      // stage advW[128 cols][16 kq] for this (ch, w): 2048 quads, 4/thread,
      // coalesced (16 consecutive lanes read 256B within one column).
#pragma unroll
      for (int r = 0; r < 4; ++r) {
        const int qq = tid + (r << 9);        // [0,2048)
        const int cl = qq >> 4, kql = qq & 15;
        int c = c0 + cl; if (c > VOCN - 1) c = VOCN - 1;  // dup tail; excluded below
        wl[(cl << 4) + (kql ^ ((cl >> 3) & 7))] =
            ld4(adv_W + (size_t)c * HN + (ch << 7) + (w << 6) + (kql << 2));
      }
      __syncthreads();
      const int kqb = w << 4;
#pragma unroll 2
      for (int kql = 0; kql < 16; ++kql) {
        const int kq = kqb + kql;
        f4 t0 = tl[(r0 << 5) + (kq ^ (r0 & 7))];
        f4 t1 = tl[((r0 + 1) << 5) + (kq ^ ((r0 + 1) & 7))];
#pragma unroll
        for (int j = 0; j < 8; ++j) {
          const int cl = (co << 3) + j;
          f4 wv = wl[(cl << 4) + (kql ^ ((cl >> 3) & 7))];
          acc0[j] = dot4(t0, wv, acc0[j]);
          acc1[j] = dot4(t1, wv, acc1[j]);
        }
      }
      __syncthreads();
    }
  }
  // per-thread, per-row argmax over its 8 cols (ascending col -> first-max ties)
  float bv0 = -3.4e38f, bv1 = -3.4e38f; int bi0 = 2147483647, bi1 = 2147483647;
#pragma unroll
  for (int j = 0; j < 8; ++j) {
    const int cl = (co << 3) + j;
    if (cl < 125) {
      if (acc0[j] > bv0) { bv0 = acc0[j]; bi0 = c0 + cl; }
      if (acc1[j] > bv1) { bv1 = acc1[j]; bi1 = c0 + cl; }
    }
  }
  float* sval = lds;                 // reuse tl region (post-sync)
  int* sidx = (int*)(lds + 1024);
  sval[(r0 << 4) + co] = bv0;  sidx[(r0 << 4) + co] = bi0;
  sval[((r0 + 1) << 4) + co] = bv1;  sidx[((r0 + 1) << 4) + co] = bi1;
  __syncthreads();
  if (tid < 64) {
    float v = sval[tid << 4]; int ii = sidx[tid << 4];
#pragma unroll
    for (int h2 = 1; h2 < 16; ++h2) {
      float v2 = sval[(tid << 4) + h2]; int i2 = sidx[(tid << 4) + h2];
      if (v2 > v || (v2 == v && i2 < ii)) { v = v2; ii = i2; }
    }
    unsigned long long key = ((unsigned long long)ord_enc(v) << 32) |
                             (unsigned long long)(0xFFFFFFFFu - (unsigned)ii);
    __hip_atomic_fetch_max(cellsS + tid, key, __ATOMIC_RELAXED,
                           __HIP_MEMORY_SCOPE_AGENT);
  }
  if (bid == 0 && tid < 64) stcg(avg_buf + tid, avgacc);
}

__global__ void __launch_bounds__(512)
seq2seq_kernel(const int* __restrict__ input, const float* __restrict__ emb_enc,
               const float* __restrict__ emb_dec,
               const float* __restrict__ enc_Wih, const float* __restrict__ enc_Whh,
               const float* __restrict__ enc_bih, const float* __restrict__ enc_bhh,
               const float* __restrict__ dec_Wih, const float* __restrict__ dec_Whh,
               const float* __restrict__ dec_bih, const float* __restrict__ dec_bhh,
               const float* __restrict__ attn_W, const float* __restrict__ attn_b,
               const float* __restrict__ comb_W, const float* __restrict__ comb_b,
               const float* __restrict__ avg_W, const float* __restrict__ adv_W,
               float* __restrict__ out, float* __restrict__ ws)
{
  __shared__ float lds[16384];  // 64KB: gru 2x32KB | d6 32KB tl + 32KB wl
  const int bid = blockIdx.x;
  int* wsi = (int*)ws;
  float* hbuf = ws + WS_H;                    // [parity][L][B][H], parity stride 65536
  unsigned long long* cells = (unsigned long long*)(ws + WS_CELLS);
  float* avg_buf = ws + WS_AVG;
  float* a_buf = ws + WS_A;
  float* applied = ws + WS_APPLIED;
  float* comb = ws + WS_COMB;
  float* gru_out = ws + WS_GRUOUT;
  float* qs_base = out + (size_t)MAXLENN * BN * HN;
  int gen = 0;

  // ---------------- encoder: software-pipelined, 1 barrier/step ----------------
#pragma unroll 1
  for (int p = 0; p <= 256; ++p) {
    if (bid < 64) {
      if (p < 256) {          // layer 0 of step p:  h0^p -> h0^{p+1}
        gru_phase(emb_enc, input + p * BN,
                  hbuf + (size_t)(p & 1) * 65536,
                  enc_Wih, enc_Whh, enc_bih, enc_bhh,
                  hbuf + (size_t)((p + 1) & 1) * 65536,
                  nullptr, bid, lds);
      }
    } else if (bid < 128) {
      if (p >= 1) {           // layer 1 of step p-1 (consumes h0^p)
        const int t = p - 1;
        gru_phase(hbuf + (size_t)((t + 1) & 1) * 65536, nullptr,
                  hbuf + (size_t)(t & 1) * 65536 + 32768,
                  enc_Wih + 786432, enc_Whh + 786432,
                  enc_bih + 1536, enc_bhh + 1536,
                  hbuf + (size_t)((t + 1) & 1) * 65536 + 32768,
                  gru_out + (size_t)t * (BN * HN), bid - 64, lds);
      }
    }
    grid_barrier(wsi, ++gen);
  }

  // One-time fence so d2's plain cached reads of (now read-only) gru_out
  // can't hit stale poison lines. This is the only cache-flush fence.
  __threadfence();

  // ---------------- decoder: 32 steps x 6 phases (d7 folded into d6/d1) -------
#pragma unroll 1
  for (int s = 0; s < 32; ++s) {
    const float* hflat = hbuf + (size_t)(s & 1) * 65536;
    float* hnew = hbuf + (size_t)((s + 1) & 1) * 65536;

    d1_attn(emb_dec, cells, s, hflat, attn_W, attn_b, a_buf, avg_buf, qs_base, bid, lds);
    grid_barrier(wsi, ++gen);

    d2_applied(a_buf, gru_out, applied, bid, lds);
    grid_barrier(wsi, ++gen);

    d3_comb(emb_dec, cells, s, applied, comb_W, comb_b, comb, bid, lds);
    grid_barrier(wsi, ++gen);

    if (bid < 64)
      gru_phase(comb, nullptr, hflat, dec_Wih, dec_Whh, dec_bih, dec_bhh,
                hnew, nullptr, bid, lds);
    grid_barrier(wsi, ++gen);

    if (bid < 64)
      gru_phase(hnew, nullptr, hflat + 32768,
                dec_Wih + 786432, dec_Whh + 786432, dec_bih + 1536, dec_bhh + 1536,
                hnew + 32768, out + (size_t)s * (BN * HN), bid, lds);
    grid_barrier(wsi, ++gen);

    d6_values(hnew + 32768, adv_W, avg_W, cells + (size_t)s * 64, avg_buf, bid, lds);
    grid_barrier(wsi, ++gen);
  }

  // finalize q for the last step (cells complete after the last barrier)
  if (bid == 0 && threadIdx.x < 64) {
    const int tid = threadIdx.x;
    unsigned long long key = __hip_atomic_load(cells + (size_t)31 * 64 + tid,
                                               __ATOMIC_RELAXED, __HIP_MEMORY_SCOPE_AGENT);
    qs_base[(size_t)31 * BN + tid] = ord_dec((unsigned)(key >> 32)) + ldcg(avg_buf + tid);
  }
}

extern "C" void kernel_launch(void* const* d_in, const int* in_sizes, int n_in,
                              void* d_out, int out_size, void* d_ws, size_t ws_size,
                              hipStream_t stream) {
  (void)in_sizes; (void)n_in; (void)out_size; (void)ws_size;
  const int* input      = (const int*)d_in[0];
  const float* emb_enc  = (const float*)d_in[1];
  const float* emb_dec  = (const float*)d_in[2];
  const float* enc_Wih  = (const float*)d_in[3];
  const float* enc_Whh  = (const float*)d_in[4];
  const float* enc_bih  = (const float*)d_in[5];
  const float* enc_bhh  = (const float*)d_in[6];
  const float* dec_Wih  = (const float*)d_in[7];
  const float* dec_Whh  = (const float*)d_in[8];
  const float* dec_bih  = (const float*)d_in[9];
  const float* dec_bhh  = (const float*)d_in[10];
  const float* attn_W   = (const float*)d_in[11];
  const float* attn_b   = (const float*)d_in[12];
  const float* comb_W   = (const float*)d_in[13];
  const float* comb_b   = (const float*)d_in[14];
  const float* avg_W    = (const float*)d_in[15];
  const float* adv_W    = (const float*)d_in[16];
  float* out = (float*)d_out;
  float* ws  = (float*)d_ws;

  hipMemsetAsync(d_ws, 0, WS_ZERO_BYTES, stream);  // barrier flags/rel + h0 + cells

  // Persistent launch: 256 blocks x 512 threads = 8 waves/CU (2/SIMD), 64KB LDS
  // -> 1 block/CU, all blocks co-resident, flag barrier safe.
  seq2seq_kernel<<<dim3(256), dim3(512), 0, stream>>>(
      input, emb_enc, emb_dec, enc_Wih, enc_Whh, enc_bih, enc_bhh,
      dec_Wih, dec_Whh, dec_bih, dec_bhh, attn_W, attn_b,
      comb_W, comb_b, avg_W, adv_W, out, ws);
}

// Round 5
// 21542.964 us; speedup vs baseline: 1.0101x; 1.0101x over previous
//
#include <hip/hip_runtime.h>
#include <math.h>

#define VOCN 32000
#define HN 512
#define TN 256
#define BN 64
#define MAXLENN 32
#define SOSW 1

// ---------------- workspace layout (float/int32 units) ----------------
#define WS_FLAG     0                       // 256 blocks * 32 ints (128B line each)
#define WS_REL      8192                    // 8 release lines * 16 ints (+pad to 256)
#define WS_H        8448                    // h buffers [2 parity][2 layer][64][512]
#define WS_CELLS    (WS_H + 131072)         // 32 steps * 64 u64 argmax cells (zeroed)
#define WS_AVG      (WS_CELLS + 4096)       // 64 floats: avg_W . top (per step)
#define WS_A        (WS_AVG + 64)           // a[64][256]  (b-major)
#define WS_APPLIED  (WS_A + 16384)          // [64][512]
#define WS_COMB     (WS_APPLIED + 32768)    // [64][512]
#define WS_GRUOUT   (WS_COMB + 32768)       // [256][64][512]
#define WS_ZERO_BYTES ((WS_CELLS + 4096) * 4) // zero flags + rel + h + cells

typedef float f4 __attribute__((ext_vector_type(4)));

__device__ __forceinline__ f4 ld4(const float* p) { return *(const f4*)p; }
// Nontemporal 16B load: compiler-managed (scoreboarded) but marked nt so the
// once-per-step 65.5MB adv_W stream doesn't evict gru_out/weights from L2.
__device__ __forceinline__ f4 ldnt4(const float* p) {
  return __builtin_nontemporal_load((const f4*)p);
}
__device__ __forceinline__ float dot4(f4 a, f4 b, float acc) {
  acc = fmaf(a.x, b.x, acc); acc = fmaf(a.y, b.y, acc);
  acc = fmaf(a.z, b.z, acc); acc = fmaf(a.w, b.w, acc); return acc;
}
__device__ __forceinline__ f4 relu4(f4 v) {
  v.x = fmaxf(v.x, 0.f); v.y = fmaxf(v.y, 0.f);
  v.z = fmaxf(v.z, 0.f); v.w = fmaxf(v.w, 0.f); return v;
}
__device__ __forceinline__ float sigmoidf_(float x) { return 1.f / (1.f + expf(-x)); }

// ---- agent-coherent (L1+L2-bypassing, sc0 sc1) loads/stores, all BLOCKING
// (waitcnt inside the asm) — the proven-safe form. They hit the coherence
// point (L3) directly; no cache-flush fences needed for cross-XCD visibility.
__device__ __forceinline__ float ldcg(const float* p) {
  float v;
  asm volatile("global_load_dword %0, %1, off sc0 sc1\n\ts_waitcnt vmcnt(0)"
               : "=&v"(v) : "v"(p) : "memory");
  return v;
}
__device__ __forceinline__ void stcg(float* p, float v) {
  asm volatile("global_store_dword %0, %1, off sc0 sc1" :: "v"(p), "v"(v) : "memory");
}
__device__ __forceinline__ void ldcg_b4(const float* p0, const float* p1,
                                        const float* p2, const float* p3,
                                        f4& v0, f4& v1, f4& v2, f4& v3) {
  asm volatile(
      "global_load_dwordx4 %0, %4, off sc0 sc1\n\t"
      "global_load_dwordx4 %1, %5, off sc0 sc1\n\t"
      "global_load_dwordx4 %2, %6, off sc0 sc1\n\t"
      "global_load_dwordx4 %3, %7, off sc0 sc1\n\t"
      "s_waitcnt vmcnt(0)"
      : "=&v"(v0), "=&v"(v1), "=&v"(v2), "=&v"(v3)
      : "v"(p0), "v"(p1), "v"(p2), "v"(p3)
      : "memory");
}
__device__ __forceinline__ void ldcg_b8(const float* p0, const float* p1,
    const float* p2, const float* p3, const float* p4, const float* p5,
    const float* p6, const float* p7,
    f4& v0, f4& v1, f4& v2, f4& v3, f4& v4, f4& v5, f4& v6, f4& v7) {
  asm volatile(
      "global_load_dwordx4 %0, %8, off sc0 sc1\n\t"
      "global_load_dwordx4 %1, %9, off sc0 sc1\n\t"
      "global_load_dwordx4 %2, %10, off sc0 sc1\n\t"
      "global_load_dwordx4 %3, %11, off sc0 sc1\n\t"
      "global_load_dwordx4 %4, %12, off sc0 sc1\n\t"
      "global_load_dwordx4 %5, %13, off sc0 sc1\n\t"
      "global_load_dwordx4 %6, %14, off sc0 sc1\n\t"
      "global_load_dwordx4 %7, %15, off sc0 sc1\n\t"
      "s_waitcnt vmcnt(0)"
      : "=&v"(v0), "=&v"(v1), "=&v"(v2), "=&v"(v3),
        "=&v"(v4), "=&v"(v5), "=&v"(v6), "=&v"(v7)
      : "v"(p0), "v"(p1), "v"(p2), "v"(p3), "v"(p4), "v"(p5), "v"(p6), "v"(p7)
      : "memory");
}
// 8 contiguous quads (128B) from one base pointer
__device__ __forceinline__ void ldcg_row8(const float* p, f4 (&v)[8]) {
  asm volatile(
      "global_load_dwordx4 %0, %8, off sc0 sc1\n\t"
      "global_load_dwordx4 %1, %8, off offset:16 sc0 sc1\n\t"
      "global_load_dwordx4 %2, %8, off offset:32 sc0 sc1\n\t"
      "global_load_dwordx4 %3, %8, off offset:48 sc0 sc1\n\t"
      "global_load_dwordx4 %4, %8, off offset:64 sc0 sc1\n\t"
      "global_load_dwordx4 %5, %8, off offset:80 sc0 sc1\n\t"
      "global_load_dwordx4 %6, %8, off offset:96 sc0 sc1\n\t"
      "global_load_dwordx4 %7, %8, off offset:112 sc0 sc1\n\t"
      "s_waitcnt vmcnt(0)"
      : "=&v"(v[0]), "=&v"(v[1]), "=&v"(v[2]), "=&v"(v[3]),
        "=&v"(v[4]), "=&v"(v[5]), "=&v"(v[6]), "=&v"(v[7])
      : "v"(p)
      : "memory");
}

// Grid barrier (512-thread-safe: only tid<256 poll flag slots; flag region has
// 256 block slots). Entry drains vmcnt so all coherent stores/atomics retire.
__device__ __forceinline__ void grid_barrier(int* wsi, int gen) {
  asm volatile("s_waitcnt vmcnt(0) lgkmcnt(0)" ::: "memory");
  __syncthreads();
  const int bid = blockIdx.x;
  const int tid = threadIdx.x;
  if (bid == 0) {
    if (tid == 0)
      __hip_atomic_store(wsi + WS_FLAG, gen, __ATOMIC_RELAXED, __HIP_MEMORY_SCOPE_AGENT);
    int* fp = wsi + WS_FLAG + (tid & 255) * 32;
    for (;;) {
      int v = gen;
      if (tid < 256)
        v = __hip_atomic_load(fp, __ATOMIC_RELAXED, __HIP_MEMORY_SCOPE_AGENT);
      if (__syncthreads_and(v >= gen)) break;
      __builtin_amdgcn_s_sleep(2);
    }
    if (tid < 8)
      __hip_atomic_store(wsi + WS_REL + tid * 16, gen, __ATOMIC_RELAXED, __HIP_MEMORY_SCOPE_AGENT);
    __syncthreads();
  } else {
    if (tid == 0) {
      __hip_atomic_store(wsi + WS_FLAG + bid * 32, gen, __ATOMIC_RELAXED, __HIP_MEMORY_SCOPE_AGENT);
      int* rp = wsi + WS_REL + (bid & 7) * 16;
      while (__hip_atomic_load(rp, __ATOMIC_RELAXED, __HIP_MEMORY_SCOPE_AGENT) < gen)
        __builtin_amdgcn_s_sleep(2);
    }
    __syncthreads();
  }
}

// Packed-argmax key helpers: key = ord(val)<<32 | (0xFFFFFFFF - idx).
// ord() is a monotone bijection float->u32; max key == max val, ties -> min idx.
__device__ __forceinline__ unsigned ord_enc(float v) {
  unsigned u = __float_as_uint(v);
  return (u & 0x80000000u) ? ~u : (u | 0x80000000u);
}
__device__ __forceinline__ float ord_dec(unsigned k32) {
  unsigned u = (k32 & 0x80000000u) ? (k32 ^ 0x80000000u) : ~k32;
  return __uint_as_float(u);
}
__device__ __forceinline__ int decode_word(const unsigned long long* cell) {
  unsigned long long key = __hip_atomic_load(cell, __ATOMIC_RELAXED,
                                             __HIP_MEMORY_SCOPE_AGENT);
  int wb = (int)(0xFFFFFFFFu - (unsigned)(key & 0xFFFFFFFFull));
  return wb < 0 ? 0 : (wb > VOCN - 1 ? VOCN - 1 : wb);
}

// GRU layer phase — 512 threads/block, 64 blocks (jg = block id). (round-4 verbatim)
__device__ __forceinline__ void gru_phase(
    const float* __restrict__ x_base, const int* __restrict__ tok,
    const float* __restrict__ h_rows,
    const float* __restrict__ Wih, const float* __restrict__ Whh,
    const float* __restrict__ bih, const float* __restrict__ bhh,
    float* __restrict__ h_out, float* __restrict__ aux_out,
    int jg, float* lds)
{
  const int tid = threadIdx.x;
  const int tid2 = tid & 255;
  const int bg = tid >> 8;             // batch half
  f4* x4l = (f4*)lds + (bg << 11);     // 2048 quads per half (32KB)
  f4* h4l = x4l + 1024;

  const float* xp[4]; const float* hp[4]; int loff[4];
#pragma unroll
  for (int i = 0; i < 4; ++i) {
    int tau = tid2 + (i << 8);
    int b = tau >> 5;        // [0,32)
    int kq = tau & 31;
    int gb = bg * 32 + b;
    const float* xr = tok ? (x_base + (size_t)tok[gb] * HN) : (x_base + (size_t)gb * HN);
    xp[i] = xr + (kq << 2);
    hp[i] = h_rows + (size_t)gb * HN + (kq << 2);
    loff[i] = (b << 5) + (kq ^ (b & 7));
  }
  const bool cachedx = (tok != nullptr);  // x = embedding table -> cached; also relu flag
  f4 pxv[4], phv[4];
  if (cachedx) {
#pragma unroll
    for (int i = 0; i < 4; ++i) pxv[i] = ld4(xp[i]);
    ldcg_b4(hp[0], hp[1], hp[2], hp[3], phv[0], phv[1], phv[2], phv[3]);
  } else {
    ldcg_b8(xp[0], xp[1], xp[2], xp[3], hp[0], hp[1], hp[2], hp[3],
            pxv[0], pxv[1], pxv[2], pxv[3], phv[0], phv[1], phv[2], phv[3]);
  }

  const int bl = tid2 & 31;
  const int jl = tid2 >> 5;         // [0,8)
  const int j = (jg << 3) + jl;     // [0,512)
  const float* wi0 = Wih + (size_t)j * HN;
  const float* wi1 = Wih + (size_t)(512 + j) * HN;
  const float* wi2 = Wih + (size_t)(1024 + j) * HN;
  const float* wh0 = Whh + (size_t)j * HN;
  const float* wh1 = Whh + (size_t)(512 + j) * HN;
  const float* wh2 = Whh + (size_t)(1024 + j) * HN;
  float ax0 = 0.f, ax1 = 0.f, ax2 = 0.f, ah0 = 0.f, ah1 = 0.f, ah2 = 0.f;
  const int rdbase = bl << 5;
  const int rdx = bl & 7;

#pragma unroll 1
  for (int ch = 0; ch < 4; ++ch) {
    __syncthreads();
#pragma unroll
    for (int i = 0; i < 4; ++i) {
      x4l[loff[i]] = cachedx ? relu4(pxv[i]) : pxv[i];
      h4l[loff[i]] = phv[i];
    }
    __syncthreads();
    if (ch < 3) {
      const int off = (ch + 1) * 128;
      if (cachedx) {
#pragma unroll
        for (int i = 0; i < 4; ++i) pxv[i] = ld4(xp[i] + off);
        ldcg_b4(hp[0] + off, hp[1] + off, hp[2] + off, hp[3] + off,
                phv[0], phv[1], phv[2], phv[3]);
      } else {
        ldcg_b8(xp[0] + off, xp[1] + off, xp[2] + off, xp[3] + off,
                hp[0] + off, hp[1] + off, hp[2] + off, hp[3] + off,
                pxv[0], pxv[1], pxv[2], pxv[3], phv[0], phv[1], phv[2], phv[3]);
      }
    }
    const int k0 = ch << 7;
#pragma unroll 4
    for (int kq = 0; kq < 32; ++kq) {
      f4 xv = x4l[rdbase + (kq ^ rdx)];
      f4 hv = h4l[rdbase + (kq ^ rdx)];
      const int kk = k0 + (kq << 2);
      ax0 = dot4(xv, ld4(wi0 + kk), ax0);
      ah0 = dot4(hv, ld4(wh0 + kk), ah0);
      ax1 = dot4(xv, ld4(wi1 + kk), ax1);
      ah1 = dot4(hv, ld4(wh1 + kk), ah1);
      ax2 = dot4(xv, ld4(wi2 + kk), ax2);
      ah2 = dot4(hv, ld4(wh2 + kk), ah2);
    }
  }
  const int gb = bg * 32 + bl;
  const float hold = ldcg(h_rows + (size_t)gb * HN + j);
  const float r = sigmoidf_(ax0 + bih[j] + ah0 + bhh[j]);
  const float z = sigmoidf_(ax1 + bih[512 + j] + ah1 + bhh[512 + j]);
  const float n = tanhf(ax2 + bih[1024 + j] + r * (ah2 + bhh[1024 + j]));
  const float hv = (1.f - z) * n + z * hold;
  stcg(h_out + (size_t)gb * HN + j, hv);
  if (aux_out) stcg(aux_out + (size_t)gb * HN + j, hv);
}

// D1 (512 thr): (round-4 verbatim)
__device__ __forceinline__ void d1_attn(
    const float* __restrict__ emb_dec, const unsigned long long* __restrict__ cells,
    int s, const float* __restrict__ hflat, const float* __restrict__ attn_W,
    const float* __restrict__ attn_b, float* __restrict__ a_buf,
    const float* __restrict__ avg_buf, float* __restrict__ qs_base,
    int bid, float* lds)
{
  const int tid = threadIdx.x;
  const int b = tid & 63, q = tid >> 6;     // q in [0,8)
  int* wlds = (int*)(lds + 576);            // 64 decoded words
  if (s > 0 && tid < 64)
    wlds[tid] = decode_word(cells + (size_t)(s - 1) * 64 + tid);
  if (s > 0 && bid == 0 && tid < 64) {
    unsigned long long key = __hip_atomic_load(cells + (size_t)(s - 1) * 64 + tid,
                                               __ATOMIC_RELAXED, __HIP_MEMORY_SCOPE_AGENT);
    qs_base[(size_t)(s - 1) * BN + tid] = ord_dec((unsigned)(key >> 32)) + ldcg(avg_buf + tid);
  }
  __syncthreads();
  const int wb = (s == 0) ? SOSW : wlds[b];
  const float* er = emb_dec + (size_t)wb * HN;
  const float* hr = hflat + b * 1024;
  const float* wr = attn_W + (size_t)bid * 1536;
  float acc = 0.f;
  const int kbeg = q * 192, kend = kbeg + 192;
  int k = kbeg;
  const int kc = (kend < 512) ? kend : 512;
  for (; k < kc; k += 4)
    acc = dot4(relu4(ld4(er + k)), ld4(wr + k), acc);
  if (k < 512) k = 512;
  for (; k < kend; k += 32) {
    f4 hv[8]; ldcg_row8(hr + (k - 512), hv);
#pragma unroll
    for (int jq = 0; jq < 8; ++jq)
      acc = dot4(hv[jq], ld4(wr + k + (jq << 2)), acc);
  }
  __syncthreads();                          // wlds consumed; reuse lds for partials
  lds[(b << 3) + q] = acc;
  __syncthreads();
  if (tid < 64) {
    float v = 0.f;
#pragma unroll
    for (int i = 0; i < 8; ++i) v += lds[(tid << 3) + i];
    v += attn_b[bid];
    stcg(a_buf + tid * 256 + bid, fmaxf(v, 0.f));
  }
}

// D2 (512 thr): applied[b,h] = sum_t a[b,t]*gru_out[t,b,h]; 4 t-quarters.
// CHANGED: 8 independent accumulators -> 8 loads in flight (was a 1-acc
// fmaf chain limiting the 32MB/step gru_out stream to ~4 outstanding).
__device__ __forceinline__ void d2_applied(const float* __restrict__ a_buf,
    const float* __restrict__ gru_out, float* __restrict__ applied, int bid, float* lds)
{
  const int tid = threadIdx.x;
  const int b = bid & 63, hc = bid >> 6;
  f4* al4 = (f4*)lds;          // 64 quads = a[b][0..256)
  float* al = lds;
  float* red = lds + 256;      // 512 partials
  if (tid < 64) {
    f4 av;
    const float* p = a_buf + b * 256 + (tid << 2);
    asm volatile("global_load_dwordx4 %0, %1, off sc0 sc1\n\ts_waitcnt vmcnt(0)"
                 : "=&v"(av) : "v"(p) : "memory");
    al4[tid] = av;
  }
  __syncthreads();
  const int hl = tid & 127, th = tid >> 7;  // th in [0,4)
  const int hh = (hc << 7) + hl;
  const float* gp = gru_out + (size_t)b * HN + hh;
  float a0 = 0.f, a1 = 0.f, a2 = 0.f, a3 = 0.f;
  float a4 = 0.f, a5 = 0.f, a6 = 0.f, a7 = 0.f;
  const int t0 = th << 6;
#pragma unroll 2
  for (int t = t0; t < t0 + 64; t += 8) {
    a0 = fmaf(al[t + 0], gp[(size_t)(t + 0) * (BN * HN)], a0);
    a1 = fmaf(al[t + 1], gp[(size_t)(t + 1) * (BN * HN)], a1);
    a2 = fmaf(al[t + 2], gp[(size_t)(t + 2) * (BN * HN)], a2);
    a3 = fmaf(al[t + 3], gp[(size_t)(t + 3) * (BN * HN)], a3);
    a4 = fmaf(al[t + 4], gp[(size_t)(t + 4) * (BN * HN)], a4);
    a5 = fmaf(al[t + 5], gp[(size_t)(t + 5) * (BN * HN)], a5);
    a6 = fmaf(al[t + 6], gp[(size_t)(t + 6) * (BN * HN)], a6);
    a7 = fmaf(al[t + 7], gp[(size_t)(t + 7) * (BN * HN)], a7);
  }
  red[tid] = ((a0 + a1) + (a2 + a3)) + ((a4 + a5) + (a6 + a7));
  __syncthreads();
  if (tid < 128)
    stcg(applied + (size_t)b * HN + (hc << 7) + tid,
         red[tid] + red[tid + 128] + red[tid + 256] + red[tid + 384]);
}

// D3 (512 thr): (round-4 verbatim)
__device__ __forceinline__ void d3_comb(const float* __restrict__ emb_dec,
    const unsigned long long* __restrict__ cells, int s,
    const float* __restrict__ applied, const float* __restrict__ comb_W,
    const float* __restrict__ comb_b, float* __restrict__ comb, int bid, float* lds)
{
  const int tid = threadIdx.x;
  const int b = tid & 63, q = tid >> 6;   // q in [0,8)
  int* wlds = (int*)(lds + 1088);         // 64 decoded words (past partial area)
  if (s > 0 && tid < 64)
    wlds[tid] = decode_word(cells + (size_t)(s - 1) * 64 + tid);
  __syncthreads();
  const int wb = (s == 0) ? SOSW : wlds[b];
  const float* er = emb_dec + (size_t)wb * HN;
  const float* apr = applied + (size_t)b * HN;
  const int col0 = bid << 1;
  const float* w0 = comb_W + (size_t)col0 * 1024;
  const float* w1 = w0 + 1024;
  float a0 = 0.f, a1 = 0.f;
  const int kb = q << 7;
  if (q < 4) {                            // emb region [0,512)
    for (int k = kb; k < kb + 128; k += 4) {
      f4 e = relu4(ld4(er + k));
      a0 = dot4(e, ld4(w0 + k), a0);
      a1 = dot4(e, ld4(w1 + k), a1);
    }
  } else {                                // applied region [512,1024): 4 rows
#pragma unroll 1
    for (int r = 0; r < 4; ++r) {
      f4 av[8]; ldcg_row8(apr + (kb - 512) + (r << 5), av);
#pragma unroll
      for (int jq = 0; jq < 8; ++jq) {
        a0 = dot4(av[jq], ld4(w0 + kb + (r << 5) + (jq << 2)), a0);
        a1 = dot4(av[jq], ld4(w1 + kb + (r << 5) + (jq << 2)), a1);
      }
    }
  }
  __syncthreads();                        // wlds consumed
  lds[(b << 3) + q] = a0;
  lds[512 + (b << 3) + q] = a1;
  __syncthreads();
  if (tid < 128) {
    const int cc = tid >> 6, b2 = tid & 63;
    const float* base = lds + cc * 512;
    float v = 0.f;
#pragma unroll
    for (int i = 0; i < 8; ++i) v += base[(b2 << 3) + i];
    v += comb_b[col0 + cc];
    stcg(comb + (size_t)b2 * HN + col0 + cc, fmaxf(v, 0.f));
  }
}

// D6 v5 (512 thr): same blocking/layout as the passing round-4 version, but
// adv_W staging is now SOFTWARE-PIPELINED through a 4-quad register buffer
// (wv) with plain NONTEMPORAL loads: tile ph+1 is issued right after the LDS
// write of tile ph, so the global-load latency hides under the tile compute
// (the proven gru pxv pattern; compiler-managed scoreboarding, no asm waits).
// 8 tiles/step: (ch in 0..4) x (w in 0..2), wl holds [128 cols][16 kq].
__device__ __forceinline__ void d6_values(const float* __restrict__ top,
    const float* __restrict__ adv_W, const float* __restrict__ avg_W,
    unsigned long long* __restrict__ cellsS, float* __restrict__ avg_buf,
    int bid, float* lds)
{
  const int tid = threadIdx.x;
  const int c0 = bid * 125;
  f4* tl = (f4*)lds;            // 2048 quads (32KB): top[64][32] swizzled
  f4* wl = ((f4*)lds) + 2048;   // 2048 quads (32KB): advW tile

  const float* tp[4]; int loff[4];
#pragma unroll
  for (int i = 0; i < 4; ++i) {
    int tau = tid + (i << 9);                 // [0,2048)
    int b = tau >> 5, kq = tau & 31;
    tp[i] = top + b * HN + (kq << 2);
    loff[i] = (b << 5) + (kq ^ (b & 7));
  }
  f4 pv[4];
  ldcg_b4(tp[0], tp[1], tp[2], tp[3], pv[0], pv[1], pv[2], pv[3]);

  // advW staging geometry: thread covers (clb + r*32, kql) for r=0..3
  const int kql = tid & 15;          // tile-local kq
  const int clb = tid >> 4;          // [0,32) column base
  int cadr[4]; int wdst[4];
#pragma unroll
  for (int r = 0; r < 4; ++r) {
    const int cl = clb + (r << 5);             // [0,128)
    int c = c0 + cl; if (c > VOCN - 1) c = VOCN - 1;   // dup tail; excluded below
    cadr[r] = c;
    wdst[r] = (cl << 4) + (kql ^ ((cl >> 3) & 7));
  }
  f4 wv[4];
#pragma unroll
  for (int r = 0; r < 4; ++r)        // prologue: tile ph=0 (ch0,w0)
    wv[r] = ldnt4(adv_W + (size_t)cadr[r] * HN + (kql << 2));

  const int rp = tid >> 4;      // [0,32) row pair (compute mapping)
  const int co = tid & 15;      // [0,16) col oct
  const int r0 = rp << 1;
  float acc0[8], acc1[8];
#pragma unroll
  for (int i = 0; i < 8; ++i) { acc0[i] = 0.f; acc1[i] = 0.f; }
  float avgacc = 0.f;

#pragma unroll 1
  for (int ph = 0; ph < 8; ++ph) {
    const int ch = ph >> 1, w = ph & 1;
    __syncthreads();
    if (w == 0) {
#pragma unroll
      for (int i = 0; i < 4; ++i) tl[loff[i]] = pv[i];
    }
#pragma unroll
    for (int r = 0; r < 4; ++r) wl[wdst[r]] = wv[r];
    __syncthreads();
    if (ph < 7) {                   // issue next advW tile (nt, compiler-managed)
      const int chn = (ph + 1) >> 1, wn = (ph + 1) & 1;
      const int koff = (chn << 7) + (wn << 6) + (kql << 2);
#pragma unroll
      for (int r = 0; r < 4; ++r)
        wv[r] = ldnt4(adv_W + (size_t)cadr[r] * HN + koff);
    }
    if (w == 0 && ch < 3) {         // issue next top chunk (coherent, blocking)
      const int off = (ch + 1) * 128;
      ldcg_b4(tp[0] + off, tp[1] + off, tp[2] + off, tp[3] + off,
              pv[0], pv[1], pv[2], pv[3]);
    }
    if (w == 0 && bid == 0 && tid < 64) {     // avg partial for row tid
#pragma unroll 4
      for (int kq = 0; kq < 32; ++kq)
        avgacc = dot4(tl[(tid << 5) + (kq ^ (tid & 7))],
                      ld4(avg_W + (ch << 7) + (kq << 2)), avgacc);
    }
    const int kqb = w << 4;
#pragma unroll 2
    for (int kqi = 0; kqi < 16; ++kqi) {
      const int kq = kqb + kqi;
      f4 t0v = tl[(r0 << 5) + (kq ^ (r0 & 7))];
      f4 t1v = tl[((r0 + 1) << 5) + (kq ^ ((r0 + 1) & 7))];
#pragma unroll
      for (int j = 0; j < 8; ++j) {
        const int cl = (co << 3) + j;
        f4 wv4 = wl[(cl << 4) + (kqi ^ ((cl >> 3) & 7))];
        acc0[j] = dot4(t0v, wv4, acc0[j]);
        acc1[j] = dot4(t1v, wv4, acc1[j]);
      }
    }
  }
  __syncthreads();   // last tile compute done before tl region is reused below

  // per-thread, per-row argmax over its 8 cols (ascending col -> first-max ties)
  float bv0 = -3.4e38f, bv1 = -3.4e38f; int bi0 = 2147483647, bi1 = 2147483647;
#pragma unroll
  for (int j = 0; j < 8; ++j) {
    const int cl = (co << 3) + j;
    if (cl < 125) {
      if (acc0[j] > bv0) { bv0 = acc0[j]; bi0 = c0 + cl; }
      if (acc1[j] > bv1) { bv1 = acc1[j]; bi1 = c0 + cl; }
    }
  }
  float* sval = lds;                 // reuse tl region (post-sync)
  int* sidx = (int*)(lds + 1024);
  sval[(r0 << 4) + co] = bv0;  sidx[(r0 << 4) + co] = bi0;
  sval[((r0 + 1) << 4) + co] = bv1;  sidx[((r0 + 1) << 4) + co] = bi1;
  __syncthreads();
  if (tid < 64) {
    float v = sval[tid << 4]; int ii = sidx[tid << 4];
#pragma unroll
    for (int h2 = 1; h2 < 16; ++h2) {
      float v2 = sval[(tid << 4) + h2]; int i2 = sidx[(tid << 4) + h2];
      if (v2 > v || (v2 == v && i2 < ii)) { v = v2; ii = i2; }
    }
    unsigned long long key = ((unsigned long long)ord_enc(v) << 32) |
                             (unsigned long long)(0xFFFFFFFFu - (unsigned)ii);
    __hip_atomic_fetch_max(cellsS + tid, key, __ATOMIC_RELAXED,
                           __HIP_MEMORY_SCOPE_AGENT);
  }
  if (bid == 0 && tid < 64) stcg(avg_buf + tid, avgacc);
}

__global__ void __launch_bounds__(512)
seq2seq_kernel(const int* __restrict__ input, const float* __restrict__ emb_enc,
               const float* __restrict__ emb_dec,
               const float* __restrict__ enc_Wih, const float* __restrict__ enc_Whh,
               const float* __restrict__ enc_bih, const float* __restrict__ enc_bhh,
               const float* __restrict__ dec_Wih, const float* __restrict__ dec_Whh,
               const float* __restrict__ dec_bih, const float* __restrict__ dec_bhh,
               const float* __restrict__ attn_W, const float* __restrict__ attn_b,
               const float* __restrict__ comb_W, const float* __restrict__ comb_b,
               const float* __restrict__ avg_W, const float* __restrict__ adv_W,
               float* __restrict__ out, float* __restrict__ ws)
{
  __shared__ float lds[16384];  // 64KB: gru 2x32KB | d6 32KB tl + 32KB wl
  const int bid = blockIdx.x;
  int* wsi = (int*)ws;
  float* hbuf = ws + WS_H;                    // [parity][L][B][H], parity stride 65536
  unsigned long long* cells = (unsigned long long*)(ws + WS_CELLS);
  float* avg_buf = ws + WS_AVG;
  float* a_buf = ws + WS_A;
  float* applied = ws + WS_APPLIED;
  float* comb = ws + WS_COMB;
  float* gru_out = ws + WS_GRUOUT;
  float* qs_base = out + (size_t)MAXLENN * BN * HN;
  int gen = 0;

  // ---------------- encoder: software-pipelined, 1 barrier/step ----------------
#pragma unroll 1
  for (int p = 0; p <= 256; ++p) {
    if (bid < 64) {
      if (p < 256) {          // layer 0 of step p:  h0^p -> h0^{p+1}
        gru_phase(emb_enc, input + p * BN,
                  hbuf + (size_t)(p & 1) * 65536,
                  enc_Wih, enc_Whh, enc_bih, enc_bhh,
                  hbuf + (size_t)((p + 1) & 1) * 65536,
                  nullptr, bid, lds);
      }
    } else if (bid < 128) {
      if (p >= 1) {           // layer 1 of step p-1 (consumes h0^p)
        const int t = p - 1;
        gru_phase(hbuf + (size_t)((t + 1) & 1) * 65536, nullptr,
                  hbuf + (size_t)(t & 1) * 65536 + 32768,
                  enc_Wih + 786432, enc_Whh + 786432,
                  enc_bih + 1536, enc_bhh + 1536,
                  hbuf + (size_t)((t + 1) & 1) * 65536 + 32768,
                  gru_out + (size_t)t * (BN * HN), bid - 64, lds);
      }
    }
    grid_barrier(wsi, ++gen);
  }

  // One-time fence so d2's plain cached reads of (now read-only) gru_out
  // can't hit stale poison lines. This is the only cache-flush fence.
  __threadfence();

  // ---------------- decoder: 32 steps x 6 phases (d7 folded into d6/d1) -------
#pragma unroll 1
  for (int s = 0; s < 32; ++s) {
    const float* hflat = hbuf + (size_t)(s & 1) * 65536;
    float* hnew = hbuf + (size_t)((s + 1) & 1) * 65536;

    d1_attn(emb_dec, cells, s, hflat, attn_W, attn_b, a_buf, avg_buf, qs_base, bid, lds);
    grid_barrier(wsi, ++gen);

    d2_applied(a_buf, gru_out, applied, bid, lds);
    grid_barrier(wsi, ++gen);

    d3_comb(emb_dec, cells, s, applied, comb_W, comb_b, comb, bid, lds);
    grid_barrier(wsi, ++gen);

    if (bid < 64)
      gru_phase(comb, nullptr, hflat, dec_Wih, dec_Whh, dec_bih, dec_bhh,
                hnew, nullptr, bid, lds);
    grid_barrier(wsi, ++gen);

    if (bid < 64)
      gru_phase(hnew, nullptr, hflat + 32768,
                dec_Wih + 786432, dec_Whh + 786432, dec_bih + 1536, dec_bhh + 1536,
                hnew + 32768, out + (size_t)s * (BN * HN), bid, lds);
    grid_barrier(wsi, ++gen);

    d6_values(hnew + 32768, adv_W, avg_W, cells + (size_t)s * 64, avg_buf, bid, lds);
    grid_barrier(wsi, ++gen);
  }

  // finalize q for the last step (cells complete after the last barrier)
  if (bid == 0 && threadIdx.x < 64) {
    const int tid = threadIdx.x;
    unsigned long long key = __hip_atomic_load(cells + (size_t)31 * 64 + tid,
                                               __ATOMIC_RELAXED, __HIP_MEMORY_SCOPE_AGENT);
    qs_base[(size_t)31 * BN + tid] = ord_dec((unsigned)(key >> 32)) + ldcg(avg_buf + tid);
  }
}

extern "C" void kernel_launch(void* const* d_in, const int* in_sizes, int n_in,
                              void* d_out, int out_size, void* d_ws, size_t ws_size,
                              hipStream_t stream) {
  (void)in_sizes; (void)n_in; (void)out_size; (void)ws_size;
  const int* input      = (const int*)d_in[0];
  const float* emb_enc  = (const float*)d_in[1];
  const float* emb_dec  = (const float*)d_in[2];
  const float* enc_Wih  = (const float*)d_in[3];
  const float* enc_Whh  = (const float*)d_in[4];
  const float* enc_bih  = (const float*)d_in[5];
  const float* enc_bhh  = (const float*)d_in[6];
  const float* dec_Wih  = (const float*)d_in[7];
  const float* dec_Whh  = (const float*)d_in[8];
  const float* dec_bih  = (const float*)d_in[9];
  const float* dec_bhh  = (const float*)d_in[10];
  const float* attn_W   = (const float*)d_in[11];
  const float* attn_b   = (const float*)d_in[12];
  const float* comb_W   = (const float*)d_in[13];
  const float* comb_b   = (const float*)d_in[14];
  const float* avg_W    = (const float*)d_in[15];
  const float* adv_W    = (const float*)d_in[16];
  float* out = (float*)d_out;
  float* ws  = (float*)d_ws;

  hipMemsetAsync(d_ws, 0, WS_ZERO_BYTES, stream);  // barrier flags/rel + h0 + cells

  // Persistent launch: 256 blocks x 512 threads = 8 waves/CU (2/SIMD), 64KB LDS
  // -> 1 block/CU, all blocks co-resident, flag barrier safe.
  seq2seq_kernel<<<dim3(256), dim3(512), 0, stream>>>(
      input, emb_enc, emb_dec, enc_Wih, enc_Whh, enc_bih, enc_bhh,
      dec_Wih, dec_Whh, dec_bih, dec_bhh, attn_W, attn_b,
      comb_W, comb_b, avg_W, adv_W, out, ws);
}

// Round 6
// 20817.302 us; speedup vs baseline: 1.0453x; 1.0349x over previous
//
#include <hip/hip_runtime.h>
#include <math.h>

#define VOCN 32000
#define HN 512
#define TN 256
#define BN 64
#define MAXLENN 32
#define SOSW 1

// ---------------- workspace layout (float/int32 units) ----------------
#define WS_FLAG     0                       // 256 blocks * 32 ints (128B line each)
#define WS_REL      8192                    // 8 release lines * 16 ints (+pad to 256)
#define WS_H        8448                    // h buffers [2 parity][2 layer][64][512]
#define WS_CELLS    (WS_H + 131072)         // 32 steps * 64 u64 argmax cells (zeroed)
#define WS_AVG      (WS_CELLS + 4096)       // 64 floats: avg_W . top (per step)
#define WS_A        (WS_AVG + 64)           // a[64][256]  (b-major)
#define WS_APPLIED  (WS_A + 16384)          // [64][512]
#define WS_COMB     (WS_APPLIED + 32768)    // [64][512]
#define WS_GRUOUT   (WS_COMB + 32768)       // [256][64][512]
#define WS_ZERO_BYTES ((WS_CELLS + 4096) * 4) // zero flags + rel + h + cells

typedef float f4 __attribute__((ext_vector_type(4)));

__device__ __forceinline__ f4 ld4(const float* p) { return *(const f4*)p; }
// Nontemporal 16B load (adv_W stream: don't evict weights from L2)
__device__ __forceinline__ f4 ldnt4(const float* p) {
  return __builtin_nontemporal_load((const f4*)p);
}
__device__ __forceinline__ float dot4(f4 a, f4 b, float acc) {
  acc = fmaf(a.x, b.x, acc); acc = fmaf(a.y, b.y, acc);
  acc = fmaf(a.z, b.z, acc); acc = fmaf(a.w, b.w, acc); return acc;
}
__device__ __forceinline__ f4 relu4(f4 v) {
  v.x = fmaxf(v.x, 0.f); v.y = fmaxf(v.y, 0.f);
  v.z = fmaxf(v.z, 0.f); v.w = fmaxf(v.w, 0.f); return v;
}
__device__ __forceinline__ float sigmoidf_(float x) { return 1.f / (1.f + expf(-x)); }

// ---- agent-coherent (L1+L2-bypassing, sc0 sc1) loads/stores, all BLOCKING.
// THEORY THIS ROUND: these serialize per-wave (~1.2us/instr) -> every phase
// has been rewritten to minimize coherent-load INSTRUCTION COUNT per wave.
__device__ __forceinline__ float ldcg(const float* p) {
  float v;
  asm volatile("global_load_dword %0, %1, off sc0 sc1\n\ts_waitcnt vmcnt(0)"
               : "=&v"(v) : "v"(p) : "memory");
  return v;
}
__device__ __forceinline__ void stcg(float* p, float v) {
  asm volatile("global_store_dword %0, %1, off sc0 sc1" :: "v"(p), "v"(v) : "memory");
}
__device__ __forceinline__ void ldcg1(const float* p, f4& v) {
  asm volatile("global_load_dwordx4 %0, %1, off sc0 sc1\n\ts_waitcnt vmcnt(0)"
               : "=&v"(v) : "v"(p) : "memory");
}
__device__ __forceinline__ void ldcg_b2(const float* p0, const float* p1,
                                        f4& v0, f4& v1) {
  asm volatile(
      "global_load_dwordx4 %0, %2, off sc0 sc1\n\t"
      "global_load_dwordx4 %1, %3, off sc0 sc1\n\t"
      "s_waitcnt vmcnt(0)"
      : "=&v"(v0), "=&v"(v1)
      : "v"(p0), "v"(p1)
      : "memory");
}
__device__ __forceinline__ void ldcg_b4(const float* p0, const float* p1,
                                        const float* p2, const float* p3,
                                        f4& v0, f4& v1, f4& v2, f4& v3) {
  asm volatile(
      "global_load_dwordx4 %0, %4, off sc0 sc1\n\t"
      "global_load_dwordx4 %1, %5, off sc0 sc1\n\t"
      "global_load_dwordx4 %2, %6, off sc0 sc1\n\t"
      "global_load_dwordx4 %3, %7, off sc0 sc1\n\t"
      "s_waitcnt vmcnt(0)"
      : "=&v"(v0), "=&v"(v1), "=&v"(v2), "=&v"(v3)
      : "v"(p0), "v"(p1), "v"(p2), "v"(p3)
      : "memory");
}

// Grid barrier (proven form, unchanged).
__device__ __forceinline__ void grid_barrier(int* wsi, int gen) {
  asm volatile("s_waitcnt vmcnt(0) lgkmcnt(0)" ::: "memory");
  __syncthreads();
  const int bid = blockIdx.x;
  const int tid = threadIdx.x;
  if (bid == 0) {
    if (tid == 0)
      __hip_atomic_store(wsi + WS_FLAG, gen, __ATOMIC_RELAXED, __HIP_MEMORY_SCOPE_AGENT);
    int* fp = wsi + WS_FLAG + (tid & 255) * 32;
    for (;;) {
      int v = gen;
      if (tid < 256)
        v = __hip_atomic_load(fp, __ATOMIC_RELAXED, __HIP_MEMORY_SCOPE_AGENT);
      if (__syncthreads_and(v >= gen)) break;
      __builtin_amdgcn_s_sleep(2);
    }
    if (tid < 8)
      __hip_atomic_store(wsi + WS_REL + tid * 16, gen, __ATOMIC_RELAXED, __HIP_MEMORY_SCOPE_AGENT);
    __syncthreads();
  } else {
    if (tid == 0) {
      __hip_atomic_store(wsi + WS_FLAG + bid * 32, gen, __ATOMIC_RELAXED, __HIP_MEMORY_SCOPE_AGENT);
      int* rp = wsi + WS_REL + (bid & 7) * 16;
      while (__hip_atomic_load(rp, __ATOMIC_RELAXED, __HIP_MEMORY_SCOPE_AGENT) < gen)
        __builtin_amdgcn_s_sleep(2);
    }
    __syncthreads();
  }
}

// Packed-argmax key helpers (unchanged).
__device__ __forceinline__ unsigned ord_enc(float v) {
  unsigned u = __float_as_uint(v);
  return (u & 0x80000000u) ? ~u : (u | 0x80000000u);
}
__device__ __forceinline__ float ord_dec(unsigned k32) {
  unsigned u = (k32 & 0x80000000u) ? (k32 ^ 0x80000000u) : ~k32;
  return __uint_as_float(u);
}
__device__ __forceinline__ int decode_word(const unsigned long long* cell) {
  unsigned long long key = __hip_atomic_load(cell, __ATOMIC_RELAXED,
                                             __HIP_MEMORY_SCOPE_AGENT);
  int wb = (int)(0xFFFFFFFFu - (unsigned)(key & 0xFFFFFFFFull));
  return wb < 0 ? 0 : (wb > VOCN - 1 ? VOCN - 1 : wb);
}

// GRU layer phase v2 — 512 thr; 64 blocks/layer = (jg in [0,32)) x (hg in {0,1}).
// Block computes 16 j x 32 b (one batch half). Staging per chunk is now
// x[32][128]+h[32][128] = 32KB -> 2+2 quads/thread -> 4 coherent instrs/wave
// (HALVED vs before). Register preload of next chunk kept (proven pattern).
__device__ __forceinline__ void gru_phase(
    const float* __restrict__ x_base, const int* __restrict__ tok,
    const float* __restrict__ h_rows,
    const float* __restrict__ Wih, const float* __restrict__ Whh,
    const float* __restrict__ bih, const float* __restrict__ bhh,
    float* __restrict__ h_out, float* __restrict__ aux_out,
    int jg, int hg, float* lds)
{
  const int tid = threadIdx.x;
  f4* x4l = (f4*)lds;          // 1024 quads (16KB): x[32 b][32 kq] swizzled
  f4* h4l = ((f4*)lds) + 1024; // 1024 quads (16KB)

  const float* xp[2]; const float* hp[2]; int loff[2];
#pragma unroll
  for (int i = 0; i < 2; ++i) {
    int qq = tid + (i << 9);     // [0,1024)
    int b = qq >> 5;             // [0,32)
    int kq = qq & 31;
    int gb = hg * 32 + b;
    const float* xr = tok ? (x_base + (size_t)tok[gb] * HN) : (x_base + (size_t)gb * HN);
    xp[i] = xr + (kq << 2);
    hp[i] = h_rows + (size_t)gb * HN + (kq << 2);
    loff[i] = (b << 5) + (kq ^ (b & 7));
  }
  const bool cachedx = (tok != nullptr);  // x = embedding table -> cached; also relu flag
  f4 pxv[2], phv[2];
  if (cachedx) {
    pxv[0] = ld4(xp[0]); pxv[1] = ld4(xp[1]);
    ldcg_b2(hp[0], hp[1], phv[0], phv[1]);
  } else {
    ldcg_b4(xp[0], xp[1], hp[0], hp[1], pxv[0], pxv[1], phv[0], phv[1]);
  }

  const int bl = tid & 31;
  const int jl = tid >> 5;          // [0,16)
  const int j = jg * 16 + jl;       // [0,512)
  const float* wi0 = Wih + (size_t)j * HN;
  const float* wi1 = Wih + (size_t)(512 + j) * HN;
  const float* wi2 = Wih + (size_t)(1024 + j) * HN;
  const float* wh0 = Whh + (size_t)j * HN;
  const float* wh1 = Whh + (size_t)(512 + j) * HN;
  const float* wh2 = Whh + (size_t)(1024 + j) * HN;
  float ax0 = 0.f, ax1 = 0.f, ax2 = 0.f, ah0 = 0.f, ah1 = 0.f, ah2 = 0.f;
  const int rdbase = bl << 5;
  const int rdx = bl & 7;

#pragma unroll 1
  for (int ch = 0; ch < 4; ++ch) {
    __syncthreads();
#pragma unroll
    for (int i = 0; i < 2; ++i) {
      x4l[loff[i]] = cachedx ? relu4(pxv[i]) : pxv[i];
      h4l[loff[i]] = phv[i];
    }
    __syncthreads();
    if (ch < 3) {
      const int off = (ch + 1) * 128;
      if (cachedx) {
        pxv[0] = ld4(xp[0] + off); pxv[1] = ld4(xp[1] + off);
        ldcg_b2(hp[0] + off, hp[1] + off, phv[0], phv[1]);
      } else {
        ldcg_b4(xp[0] + off, xp[1] + off, hp[0] + off, hp[1] + off,
                pxv[0], pxv[1], phv[0], phv[1]);
      }
    }
    const int k0 = ch << 7;
#pragma unroll 4
    for (int kq = 0; kq < 32; ++kq) {
      f4 xv = x4l[rdbase + (kq ^ rdx)];
      f4 hv = h4l[rdbase + (kq ^ rdx)];
      const int kk = k0 + (kq << 2);
      ax0 = dot4(xv, ld4(wi0 + kk), ax0);
      ah0 = dot4(hv, ld4(wh0 + kk), ah0);
      ax1 = dot4(xv, ld4(wi1 + kk), ax1);
      ah1 = dot4(hv, ld4(wh1 + kk), ah1);
      ax2 = dot4(xv, ld4(wi2 + kk), ax2);
      ah2 = dot4(hv, ld4(wh2 + kk), ah2);
    }
  }
  const int gb = hg * 32 + bl;
  const float hold = ldcg(h_rows + (size_t)gb * HN + j);
  const float r = sigmoidf_(ax0 + bih[j] + ah0 + bhh[j]);
  const float z = sigmoidf_(ax1 + bih[512 + j] + ah1 + bhh[512 + j]);
  const float n = tanhf(ax2 + bih[1024 + j] + r * (ah2 + bhh[1024 + j]));
  const float hv = (1.f - z) * n + z * hold;
  stcg(h_out + (size_t)gb * HN + j, hv);
  if (aux_out) stcg(aux_out + (size_t)gb * HN + j, hv);
}

// D1 v2 — 2D split: 256 blocks = (bg in [0,16)) x (tg in [0,16)).
// Block covers b in [bg*4,+4), t in [tg*16,+16). Stages cat(e,sv) for its 4 b
// into LDS ONCE: h via 2 coherent instrs/wave (was 48), e plain+relu.
// sv is the RAW C-order reshape: sv[b][r] = hflat[b*1024 + r].
__device__ __forceinline__ void d1_attn(
    const float* __restrict__ emb_dec, const unsigned long long* __restrict__ cells,
    int s, const float* __restrict__ hflat, const float* __restrict__ attn_W,
    const float* __restrict__ attn_b, float* __restrict__ a_buf,
    const float* __restrict__ avg_buf, float* __restrict__ qs_base,
    int bid, float* lds)
{
  const int tid = threadIdx.x;
  const int bg = bid >> 4, tg = bid & 15;
  f4* catq = (f4*)lds;                 // 4 rows x 384 quads = 24KB
  float* redl = lds + 6144;            // 512 floats
  int* wlds = (int*)(lds + 6656);      // 4 words
  if (tid < 4)
    wlds[tid] = (s == 0) ? SOSW
              : decode_word(cells + (size_t)(s - 1) * 64 + bg * 4 + tid);
  if (s > 0 && bid == 0 && tid < 64) {  // finalize step s-1's q output
    unsigned long long key = __hip_atomic_load(cells + (size_t)(s - 1) * 64 + tid,
                                               __ATOMIC_RELAXED, __HIP_MEMORY_SCOPE_AGENT);
    qs_base[(size_t)(s - 1) * BN + tid] = ord_dec((unsigned)(key >> 32)) + ldcg(avg_buf + tid);
  }
  __syncthreads();
  {  // stage h (coherent): 1024 quads; thread covers qq in {tid, tid+512}
    const int b0 = tid >> 8, r0q = tid & 255;
    const int b1 = b0 + 2,   r1q = r0q;
    f4 h0, h1;
    ldcg_b2(hflat + (size_t)(bg * 4 + b0) * 1024 + (r0q << 2),
            hflat + (size_t)(bg * 4 + b1) * 1024 + (r1q << 2), h0, h1);
    catq[b0 * 384 + 128 + r0q] = h0;
    catq[b1 * 384 + 128 + r1q] = h1;
  }
  {  // stage e (plain cached, relu): 512 quads, 1/thread
    const int b = tid >> 7, kq = tid & 127;
    const float* er = emb_dec + (size_t)wlds[b] * HN;
    catq[b * 384 + kq] = relu4(ld4(er + (kq << 2)));
  }
  __syncthreads();
  // compute: wave = one seg (o spans 0..63 -> 4 bi broadcast reads)
  const int o = tid & 63, seg = tid >> 6;      // seg in [0,8)
  const int bi = o >> 4, ti = o & 15;
  const int t = tg * 16 + ti;
  const float* wr = attn_W + (size_t)t * 1536 + seg * 192;
  const f4* cb = catq + bi * 384 + seg * 48;
  float acc = 0.f;
#pragma unroll 8
  for (int qi = 0; qi < 48; ++qi)
    acc = dot4(cb[qi], ld4(wr + (qi << 2)), acc);
  redl[o * 8 + seg] = acc;
  __syncthreads();
  if (tid < 64) {
    float v = 0.f;
#pragma unroll
    for (int i = 0; i < 8; ++i) v += redl[tid * 8 + i];
    const int b = bg * 4 + (tid >> 4), t2 = tg * 16 + (tid & 15);
    v += attn_b[t2];
    stcg(a_buf + b * 256 + t2, fmaxf(v, 0.f));
  }
}

// D2 (round-5 verbatim): applied[b,h] = sum_t a[b,t]*gru_out[t,b,h].
__device__ __forceinline__ void d2_applied(const float* __restrict__ a_buf,
    const float* __restrict__ gru_out, float* __restrict__ applied, int bid, float* lds)
{
  const int tid = threadIdx.x;
  const int b = bid & 63, hc = bid >> 6;
  f4* al4 = (f4*)lds;
  float* al = lds;
  float* red = lds + 256;
  if (tid < 64) {
    f4 av;
    const float* p = a_buf + b * 256 + (tid << 2);
    asm volatile("global_load_dwordx4 %0, %1, off sc0 sc1\n\ts_waitcnt vmcnt(0)"
                 : "=&v"(av) : "v"(p) : "memory");
    al4[tid] = av;
  }
  __syncthreads();
  const int hl = tid & 127, th = tid >> 7;
  const int hh = (hc << 7) + hl;
  const float* gp = gru_out + (size_t)b * HN + hh;
  float a0 = 0.f, a1 = 0.f, a2 = 0.f, a3 = 0.f;
  float a4 = 0.f, a5 = 0.f, a6 = 0.f, a7 = 0.f;
  const int t0 = th << 6;
#pragma unroll 2
  for (int t = t0; t < t0 + 64; t += 8) {
    a0 = fmaf(al[t + 0], gp[(size_t)(t + 0) * (BN * HN)], a0);
    a1 = fmaf(al[t + 1], gp[(size_t)(t + 1) * (BN * HN)], a1);
    a2 = fmaf(al[t + 2], gp[(size_t)(t + 2) * (BN * HN)], a2);
    a3 = fmaf(al[t + 3], gp[(size_t)(t + 3) * (BN * HN)], a3);
    a4 = fmaf(al[t + 4], gp[(size_t)(t + 4) * (BN * HN)], a4);
    a5 = fmaf(al[t + 5], gp[(size_t)(t + 5) * (BN * HN)], a5);
    a6 = fmaf(al[t + 6], gp[(size_t)(t + 6) * (BN * HN)], a6);
    a7 = fmaf(al[t + 7], gp[(size_t)(t + 7) * (BN * HN)], a7);
  }
  red[tid] = ((a0 + a1) + (a2 + a3)) + ((a4 + a5) + (a6 + a7));
  __syncthreads();
  if (tid < 128)
    stcg(applied + (size_t)b * HN + (hc << 7) + tid,
         red[tid] + red[tid + 128] + red[tid + 256] + red[tid + 384]);
}

// D3 v2 — 2D split: 256 blocks = (bg = bid&15) x (cg = bid>>4).
// Block covers b in [bg*4,+4), cols [cg*32,+32). Stages cat(e,applied) for its
// 4 b once: applied via 1 coherent instr/wave (was 32), e plain+relu.
__device__ __forceinline__ void d3_comb(const float* __restrict__ emb_dec,
    const unsigned long long* __restrict__ cells, int s,
    const float* __restrict__ applied, const float* __restrict__ comb_W,
    const float* __restrict__ comb_b, float* __restrict__ comb, int bid, float* lds)
{
  const int tid = threadIdx.x;
  const int bg = bid & 15, cg = bid >> 4;
  f4* cat2q = (f4*)lds;            // 4 rows x 256 quads = 16KB
  float* red2 = lds + 4096;        // 512 floats
  int* wlds = (int*)(lds + 4608);  // 4 words
  if (tid < 4)
    wlds[tid] = (s == 0) ? SOSW
              : decode_word(cells + (size_t)(s - 1) * 64 + bg * 4 + tid);
  __syncthreads();
  {  // stage applied (coherent): 512 quads, 1/thread
    const int b = tid >> 7, kq = tid & 127;
    f4 av;
    ldcg1(applied + (size_t)(bg * 4 + b) * HN + (kq << 2), av);
    cat2q[b * 256 + 128 + kq] = av;
  }
  {  // stage e (plain, relu): 512 quads, 1/thread
    const int b = tid >> 7, kq = tid & 127;
    cat2q[b * 256 + kq] = relu4(ld4(emb_dec + (size_t)wlds[b] * HN + (kq << 2)));
  }
  __syncthreads();
  const int o = tid & 127, seg = tid >> 7;     // seg in [0,4)
  const int bi = o >> 5, cj = o & 31;
  const int col = cg * 32 + cj;
  const float* wr = comb_W + (size_t)col * 1024 + seg * 256;
  const f4* cb = cat2q + bi * 256 + seg * 64;
  float acc = 0.f;
#pragma unroll 8
  for (int qi = 0; qi < 64; ++qi)
    acc = dot4(cb[qi], ld4(wr + (qi << 2)), acc);
  red2[o * 4 + seg] = acc;
  __syncthreads();
  if (tid < 128) {
    const int b = bg * 4 + (tid >> 5), c2 = cg * 32 + (tid & 31);
    float v = red2[tid * 4] + red2[tid * 4 + 1] + red2[tid * 4 + 2] + red2[tid * 4 + 3];
    v += comb_b[c2];
    stcg(comb + (size_t)b * HN + c2, fmaxf(v, 0.f));
  }
}

// D6 (round-5 verbatim): per-block partial argmax over 125 adv_W columns.
__device__ __forceinline__ void d6_values(const float* __restrict__ top,
    const float* __restrict__ adv_W, const float* __restrict__ avg_W,
    unsigned long long* __restrict__ cellsS, float* __restrict__ avg_buf,
    int bid, float* lds)
{
  const int tid = threadIdx.x;
  const int c0 = bid * 125;
  f4* tl = (f4*)lds;            // 2048 quads (32KB): top[64][32] swizzled
  f4* wl = ((f4*)lds) + 2048;   // 2048 quads (32KB): advW tile

  const float* tp[4]; int loff[4];
#pragma unroll
  for (int i = 0; i < 4; ++i) {
    int tau = tid + (i << 9);                 // [0,2048)
    int b = tau >> 5, kq = tau & 31;
    tp[i] = top + b * HN + (kq << 2);
    loff[i] = (b << 5) + (kq ^ (b & 7));
  }
  f4 pv[4];
  ldcg_b4(tp[0], tp[1], tp[2], tp[3], pv[0], pv[1], pv[2], pv[3]);

  const int kql = tid & 15;          // tile-local kq
  const int clb = tid >> 4;          // [0,32) column base
  int cadr[4]; int wdst[4];
#pragma unroll
  for (int r = 0; r < 4; ++r) {
    const int cl = clb + (r << 5);             // [0,128)
    int c = c0 + cl; if (c > VOCN - 1) c = VOCN - 1;
    cadr[r] = c;
    wdst[r] = (cl << 4) + (kql ^ ((cl >> 3) & 7));
  }
  f4 wv[4];
#pragma unroll
  for (int r = 0; r < 4; ++r)
    wv[r] = ldnt4(adv_W + (size_t)cadr[r] * HN + (kql << 2));

  const int rp = tid >> 4;
  const int co = tid & 15;
  const int r0 = rp << 1;
  float acc0[8], acc1[8];
#pragma unroll
  for (int i = 0; i < 8; ++i) { acc0[i] = 0.f; acc1[i] = 0.f; }
  float avgacc = 0.f;

#pragma unroll 1
  for (int ph = 0; ph < 8; ++ph) {
    const int ch = ph >> 1, w = ph & 1;
    __syncthreads();
    if (w == 0) {
#pragma unroll
      for (int i = 0; i < 4; ++i) tl[loff[i]] = pv[i];
    }
#pragma unroll
    for (int r = 0; r < 4; ++r) wl[wdst[r]] = wv[r];
    __syncthreads();
    if (ph < 7) {
      const int chn = (ph + 1) >> 1, wn = (ph + 1) & 1;
      const int koff = (chn << 7) + (wn << 6) + (kql << 2);
#pragma unroll
      for (int r = 0; r < 4; ++r)
        wv[r] = ldnt4(adv_W + (size_t)cadr[r] * HN + koff);
    }
    if (w == 0 && ch < 3) {
      const int off = (ch + 1) * 128;
      ldcg_b4(tp[0] + off, tp[1] + off, tp[2] + off, tp[3] + off,
              pv[0], pv[1], pv[2], pv[3]);
    }
    if (w == 0 && bid == 0 && tid < 64) {
#pragma unroll 4
      for (int kq = 0; kq < 32; ++kq)
        avgacc = dot4(tl[(tid << 5) + (kq ^ (tid & 7))],
                      ld4(avg_W + (ch << 7) + (kq << 2)), avgacc);
    }
    const int kqb = w << 4;
#pragma unroll 2
    for (int kqi = 0; kqi < 16; ++kqi) {
      const int kq = kqb + kqi;
      f4 t0v = tl[(r0 << 5) + (kq ^ (r0 & 7))];
      f4 t1v = tl[((r0 + 1) << 5) + (kq ^ ((r0 + 1) & 7))];
#pragma unroll
      for (int j = 0; j < 8; ++j) {
        const int cl = (co << 3) + j;
        f4 wv4 = wl[(cl << 4) + (kqi ^ ((cl >> 3) & 7))];
        acc0[j] = dot4(t0v, wv4, acc0[j]);
        acc1[j] = dot4(t1v, wv4, acc1[j]);
      }
    }
  }
  __syncthreads();

  float bv0 = -3.4e38f, bv1 = -3.4e38f; int bi0 = 2147483647, bi1 = 2147483647;
#pragma unroll
  for (int j = 0; j < 8; ++j) {
    const int cl = (co << 3) + j;
    if (cl < 125) {
      if (acc0[j] > bv0) { bv0 = acc0[j]; bi0 = c0 + cl; }
      if (acc1[j] > bv1) { bv1 = acc1[j]; bi1 = c0 + cl; }
    }
  }
  float* sval = lds;
  int* sidx = (int*)(lds + 1024);
  sval[(r0 << 4) + co] = bv0;  sidx[(r0 << 4) + co] = bi0;
  sval[((r0 + 1) << 4) + co] = bv1;  sidx[((r0 + 1) << 4) + co] = bi1;
  __syncthreads();
  if (tid < 64) {
    float v = sval[tid << 4]; int ii = sidx[tid << 4];
#pragma unroll
    for (int h2 = 1; h2 < 16; ++h2) {
      float v2 = sval[(tid << 4) + h2]; int i2 = sidx[(tid << 4) + h2];
      if (v2 > v || (v2 == v && i2 < ii)) { v = v2; ii = i2; }
    }
    unsigned long long key = ((unsigned long long)ord_enc(v) << 32) |
                             (unsigned long long)(0xFFFFFFFFu - (unsigned)ii);
    __hip_atomic_fetch_max(cellsS + tid, key, __ATOMIC_RELAXED,
                           __HIP_MEMORY_SCOPE_AGENT);
  }
  if (bid == 0 && tid < 64) stcg(avg_buf + tid, avgacc);
}

__global__ void __launch_bounds__(512)
seq2seq_kernel(const int* __restrict__ input, const float* __restrict__ emb_enc,
               const float* __restrict__ emb_dec,
               const float* __restrict__ enc_Wih, const float* __restrict__ enc_Whh,
               const float* __restrict__ enc_bih, const float* __restrict__ enc_bhh,
               const float* __restrict__ dec_Wih, const float* __restrict__ dec_Whh,
               const float* __restrict__ dec_bih, const float* __restrict__ dec_bhh,
               const float* __restrict__ attn_W, const float* __restrict__ attn_b,
               const float* __restrict__ comb_W, const float* __restrict__ comb_b,
               const float* __restrict__ avg_W, const float* __restrict__ adv_W,
               float* __restrict__ out, float* __restrict__ ws)
{
  __shared__ float lds[16384];  // 64KB: gru 32KB | d1 27KB | d3 19KB | d6 64KB
  const int bid = blockIdx.x;
  int* wsi = (int*)ws;
  float* hbuf = ws + WS_H;                    // [parity][L][B][H], parity stride 65536
  unsigned long long* cells = (unsigned long long*)(ws + WS_CELLS);
  float* avg_buf = ws + WS_AVG;
  float* a_buf = ws + WS_A;
  float* applied = ws + WS_APPLIED;
  float* comb = ws + WS_COMB;
  float* gru_out = ws + WS_GRUOUT;
  float* qs_base = out + (size_t)MAXLENN * BN * HN;
  int gen = 0;

  // ---------------- encoder: software-pipelined, 1 barrier/step ----------------
  // Layer 0: blocks 0..63 (jg=bid>>1, hg=bid&1); Layer 1: blocks 64..127.
#pragma unroll 1
  for (int p = 0; p <= 256; ++p) {
    if (bid < 64) {
      if (p < 256) {          // layer 0 of step p:  h0^p -> h0^{p+1}
        gru_phase(emb_enc, input + p * BN,
                  hbuf + (size_t)(p & 1) * 65536,
                  enc_Wih, enc_Whh, enc_bih, enc_bhh,
                  hbuf + (size_t)((p + 1) & 1) * 65536,
                  nullptr, bid >> 1, bid & 1, lds);
      }
    } else if (bid < 128) {
      if (p >= 1) {           // layer 1 of step p-1 (consumes h0^p)
        const int t = p - 1;
        const int rb = bid - 64;
        gru_phase(hbuf + (size_t)((t + 1) & 1) * 65536, nullptr,
                  hbuf + (size_t)(t & 1) * 65536 + 32768,
                  enc_Wih + 786432, enc_Whh + 786432,
                  enc_bih + 1536, enc_bhh + 1536,
                  hbuf + (size_t)((t + 1) & 1) * 65536 + 32768,
                  gru_out + (size_t)t * (BN * HN), rb >> 1, rb & 1, lds);
      }
    }
    grid_barrier(wsi, ++gen);
  }

  // One-time fence so d2's plain cached reads of (now read-only) gru_out
  // can't hit stale poison lines. This is the only cache-flush fence.
  __threadfence();

  // ---------------- decoder: 32 steps x 6 phases (d7 folded into d6/d1) -------
#pragma unroll 1
  for (int s = 0; s < 32; ++s) {
    const float* hflat = hbuf + (size_t)(s & 1) * 65536;
    float* hnew = hbuf + (size_t)((s + 1) & 1) * 65536;

    d1_attn(emb_dec, cells, s, hflat, attn_W, attn_b, a_buf, avg_buf, qs_base, bid, lds);
    grid_barrier(wsi, ++gen);

    d2_applied(a_buf, gru_out, applied, bid, lds);
    grid_barrier(wsi, ++gen);

    d3_comb(emb_dec, cells, s, applied, comb_W, comb_b, comb, bid, lds);
    grid_barrier(wsi, ++gen);

    if (bid < 64)
      gru_phase(comb, nullptr, hflat, dec_Wih, dec_Whh, dec_bih, dec_bhh,
                hnew, nullptr, bid >> 1, bid & 1, lds);
    grid_barrier(wsi, ++gen);

    if (bid < 64)
      gru_phase(hnew, nullptr, hflat + 32768,
                dec_Wih + 786432, dec_Whh + 786432, dec_bih + 1536, dec_bhh + 1536,
                hnew + 32768, out + (size_t)s * (BN * HN), bid >> 1, bid & 1, lds);
    grid_barrier(wsi, ++gen);

    d6_values(hnew + 32768, adv_W, avg_W, cells + (size_t)s * 64, avg_buf, bid, lds);
    grid_barrier(wsi, ++gen);
  }

  // finalize q for the last step (cells complete after the last barrier)
  if (bid == 0 && threadIdx.x < 64) {
    const int tid = threadIdx.x;
    unsigned long long key = __hip_atomic_load(cells + (size_t)31 * 64 + tid,
                                               __ATOMIC_RELAXED, __HIP_MEMORY_SCOPE_AGENT);
    qs_base[(size_t)31 * BN + tid] = ord_dec((unsigned)(key >> 32)) + ldcg(avg_buf + tid);
  }
}

extern "C" void kernel_launch(void* const* d_in, const int* in_sizes, int n_in,
                              void* d_out, int out_size, void* d_ws, size_t ws_size,
                              hipStream_t stream) {
  (void)in_sizes; (void)n_in; (void)out_size; (void)ws_size;
  const int* input      = (const int*)d_in[0];
  const float* emb_enc  = (const float*)d_in[1];
  const float* emb_dec  = (const float*)d_in[2];
  const float* enc_Wih  = (const float*)d_in[3];
  const float* enc_Whh  = (const float*)d_in[4];
  const float* enc_bih  = (const float*)d_in[5];
  const float* enc_bhh  = (const float*)d_in[6];
  const float* dec_Wih  = (const float*)d_in[7];
  const float* dec_Whh  = (const float*)d_in[8];
  const float* dec_bih  = (const float*)d_in[9];
  const float* dec_bhh  = (const float*)d_in[10];
  const float* attn_W   = (const float*)d_in[11];
  const float* attn_b   = (const float*)d_in[12];
  const float* comb_W   = (const float*)d_in[13];
  const float* comb_b   = (const float*)d_in[14];
  const float* avg_W    = (const float*)d_in[15];
  const float* adv_W    = (const float*)d_in[16];
  float* out = (float*)d_out;
  float* ws  = (float*)d_ws;

  hipMemsetAsync(d_ws, 0, WS_ZERO_BYTES, stream);  // barrier flags/rel + h0 + cells

  // Persistent launch: 256 blocks x 512 threads = 8 waves/CU (2/SIMD), 64KB LDS
  // -> 1 block/CU, all blocks co-resident, flag barrier safe.
  seq2seq_kernel<<<dim3(256), dim3(512), 0, stream>>>(
      input, emb_enc, emb_dec, enc_Wih, enc_Whh, enc_bih, enc_bhh,
      dec_Wih, dec_Whh, dec_bih, dec_bhh, attn_W, attn_b,
      comb_W, comb_b, avg_W, adv_W, out, ws);
}